// Round 6
// baseline (77.271 us; speedup 1.0000x reference)
//
#include <hip/hip_runtime.h>

namespace {

constexpr int   kC    = 80;
constexpr int   kD    = 8525;
constexpr int   kB    = 64;
constexpr float kEps  = 1e-6f;
constexpr int   kOC   = 85;                  // outs channels
constexpr int   kGC   = 88;                  // gres channels
constexpr int   kBlk  = 256;
constexpr int   kPB   = kD * kOC;            // 724625 floats per batch item

constexpr int   kRowPerB    = 6;             // row blocks per batch item
constexpr int   kNRow       = kB * kRowPerB; // 384 row blocks (dispatched first)
constexpr int   kStreamPerB = 26;            // stream blocks per batch item
constexpr int   kNStream    = kB * kStreamPerB;  // 1664
constexpr int   kNT         = kNRow + kNStream;  // 2048 total
constexpr int   kChunk = (kPB + kStreamPerB - 1) / kStreamPerB;  // 27871
constexpr int   kRPB   = (kD + kRowPerB - 1) / kRowPerB;         // 1421 rows

constexpr int   kQCap = 320;   // pos-row queue capacity (mean ~142, +15 sigma)
constexpr int   kQW   = 8;     // words per queue entry

__device__ __forceinline__ float wave_reduce(float v) {
#pragma unroll
  for (int o = 32; o > 0; o >>= 1) v += __shfl_down(v, o, 64);
  return v;
}

__device__ __forceinline__ float fast_rcp(float x) {
  return __builtin_amdgcn_rcpf(x);
}

// raw neg-loss term: p^2 * log(1-p+eps), p = sigmoid(x)
__device__ __forceinline__ float lneg_raw(float x) {
  const float p = fast_rcp(1.0f + __expf(-x));
  return p * p * __logf(1.0f - p + kEps);
}

__device__ __forceinline__ float lneg4(const float4 v) {
  return (lneg_raw(v.x) + lneg_raw(v.y)) + (lneg_raw(v.z) + lneg_raw(v.w));
}

__global__ __launch_bounds__(kBlk, 8) void floss_fused(
    const float* __restrict__ outs, const float* __restrict__ gres,
    const float* __restrict__ grids, const int* __restrict__ nums_pos,
    float* __restrict__ partials) {
  const int bid = blockIdx.x;
  const int tid = threadIdx.x;

  __shared__ float s_q[kQCap * kQW];
  __shared__ int   s_cnt;
  __shared__ float sm[3][kBlk / 64];

  float pm = 0.f, pr = 0.f, pn = 0.f;

  if (bid >= kNRow) {
    // =========== STREAM BLOCK: branchless lneg over a flat range ==========
    const int sid = bid - kNRow;
    const int b   = sid / kStreamPerB;
    const int s   = sid - b * kStreamPerB;
    const float scale = fast_rcp(64.0f * (float)nums_pos[b]);
    const int e0 = s * kChunk;
    const int e1 = (e0 + kChunk < kPB) ? e0 + kChunk : kPB;
    const int gA = b * kPB + e0;
    const int gB = b * kPB + e1;
    const int gv = (gA + 3) & ~3;
    const int nvec = (gB - gv) >> 2;
    const int gvend = gv + (nvec << 2);
    float a0 = 0.f, a1 = 0.f, a2 = 0.f, a3 = 0.f;
    if (tid < gv - gA)    a0 += lneg_raw(outs[gA + tid]);
    if (tid < gB - gvend) a1 += lneg_raw(outs[gvend + tid]);
    const float* pv = outs + gv;
    int v = tid;
    for (; v + 3 * kBlk < nvec; v += 4 * kBlk) {
      const float4 xa = *(const float4*)(pv + 4 * v);
      const float4 xb = *(const float4*)(pv + 4 * (v + kBlk));
      const float4 xc = *(const float4*)(pv + 4 * (v + 2 * kBlk));
      const float4 xd = *(const float4*)(pv + 4 * (v + 3 * kBlk));
      a0 += lneg4(xa);
      a1 += lneg4(xb);
      a2 += lneg4(xc);
      a3 += lneg4(xd);
    }
    for (; v < nvec; v += kBlk) a0 += lneg4(*(const float4*)(pv + 4 * v));
    pm = -0.75f * scale * ((a0 + a1) + (a2 + a3));
  } else {
    // =========== ROW BLOCK: tail-fix + conf + pos queue + scans ===========
    const int b  = bid / kRowPerB;
    const int s  = bid - b * kRowPerB;
    const int r0 = s * kRPB;
    const int r1 = (r0 + kRPB < kD) ? r0 + kRPB : kD;
    const float scale = fast_rcp(64.0f * (float)nums_pos[b]);

    if (tid == 0) s_cnt = 0;
    __syncthreads();

    // stage 1: one row per lane, all loads lane-independent
    for (int r = r0 + tid; r < r1; r += kBlk) {
      const int row = b * kD + r;
      const float4 xt = *(const float4*)(outs + (size_t)row * kOC + 80);
      const float  x84 = outs[(size_t)row * kOC + 84];
      const float4 t1 = *(const float4*)(gres + (size_t)row * kGC + 84);
      // remove the 5 tail-channel lneg contributions the stream added
      const float t5 = ((lneg_raw(xt.x) + lneg_raw(xt.y)) +
                        (lneg_raw(xt.z) + lneg_raw(xt.w))) + lneg_raw(x84);
      pm += 0.75f * scale * t5;
      if (t1.y == 1.0f) {  // mask_pp -> conf BCE on x80
        const float pc = fast_rcp(1.0f + __expf(-xt.x));
        pm += -5.0f * __logf(pc + kEps) * scale;
      }
      if (t1.z == 1.0f) {  // mask_pos
        pn += 1.0f;
        const int slot = atomicAdd(&s_cnt, 1);
        if (slot < kQCap) {
          float* q = s_q + slot * kQW;
          q[0] = __int_as_float(row);
          q[1] = xt.y; q[2] = xt.z; q[3] = xt.w; q[4] = x84;  // pred offsets
          q[5] = grids[2 * r + 0];
          q[6] = grids[2 * r + 1];
          q[7] = t1.x;                                        // g_ltrb.b (c84)
        }
      }
    }
    __syncthreads();

    // stage 2: half-wave per queued pos row
    const int nq = (s_cnt < kQCap) ? s_cnt : kQCap;
    const int hh = tid >> 5;   // half-wave id 0..7
    const int h  = tid & 31;
    for (int e = hh; e < nq; e += 8) {
      const float* q = s_q + e * kQW;
      const int row = __float_as_int(q[0]);
      int cand = -1;
      float4 v = make_float4(0.f, 0.f, 0.f, 0.f);
      if (h < 20) {
        v = *(const float4*)(gres + (size_t)row * kGC + 4 * h);
        if (v.x == 1.0f) cand = 4 * h;
        if (v.y == 1.0f) cand = 4 * h + 1;
        if (v.z == 1.0f) cand = 4 * h + 2;
        if (v.w == 1.0f) cand = 4 * h + 3;
      } else if (h == 20) {
        v = *(const float4*)(gres + (size_t)row * kGC + 80);  // gcen,l,t,r
      }
#pragma unroll
      for (int m = 16; m > 0; m >>= 1) {
        const int o = __shfl_xor(cand, m, 32);
        cand = (o > cand) ? o : cand;
      }
      if (h == 20 && cand >= 0) {
        // correction at label channel: + l_pos - l_neg
        const float x  = outs[(size_t)row * kOC + cand];
        const float p  = fast_rcp(1.0f + __expf(-x));
        const float om = 1.0f - p;
        const float lp = -0.25f * om * om * __logf(p + kEps);
        const float ln = -0.75f * p * p * __logf(om + kEps);
        pm += (lp - ln) * scale;
        // GIoU regression
        const float gx = q[5], gy = q[6];
        const float p0 = gx - q[1], p1 = gy - q[2];
        const float p2 = gx + q[3], p3 = gy + q[4];
        const float g0 = v.y, g1 = v.z, g2 = v.w, g3 = q[7];
        const float iw = fmaxf(fminf(p2, g2) - fmaxf(p0, g0), 0.f);
        const float ih = fmaxf(fminf(p3, g3) - fmaxf(p1, g1), 0.f);
        const float inter = iw * ih;
        const float ap = fmaxf(p2 - p0, 0.f) * fmaxf(p3 - p1, 0.f);
        const float ag = fmaxf(g2 - g0, 0.f) * fmaxf(g3 - g1, 0.f);
        const float un = ap + ag - inter;
        const float iou = inter * fast_rcp(un + kEps);
        const float ca = (fmaxf(p2, g2) - fminf(p0, g0)) *
                         (fmaxf(p3, g3) - fminf(p1, g1));
        const float giou = iou - (ca - un) * fast_rcp(ca + kEps);
        pr += (1.0f - giou) * v.x;
      }
    }
  }

  // =========== block reduction + partial write ===========================
  const float vm = wave_reduce(pm);
  const float vr = wave_reduce(pr);
  const float vn = wave_reduce(pn);
  const int lane = tid & 63;
  const int w    = tid >> 6;
  if (lane == 0) { sm[0][w] = vm; sm[1][w] = vr; sm[2][w] = vn; }
  __syncthreads();
  if (tid == 0) {
    float m = 0.f, r = 0.f, n = 0.f;
#pragma unroll
    for (int j = 0; j < kBlk / 64; ++j) { m += sm[0][j]; r += sm[1][j]; n += sm[2][j]; }
    partials[bid * 3 + 0] = m;
    partials[bid * 3 + 1] = r;
    partials[bid * 3 + 2] = n;
  }
}

__global__ __launch_bounds__(kBlk) void floss_final(
    const float* __restrict__ partials, float* __restrict__ out) {
  float m = 0.f, r = 0.f, n = 0.f;
  for (int i = threadIdx.x; i < kNT; i += kBlk) {
    m += partials[i * 3 + 0];
    r += partials[i * 3 + 1];
    n += partials[i * 3 + 2];
  }
  __shared__ float sm[3][kBlk / 64];
  m = wave_reduce(m); r = wave_reduce(r); n = wave_reduce(n);
  const int lane = threadIdx.x & 63;
  const int w    = threadIdx.x >> 6;
  if (lane == 0) { sm[0][w] = m; sm[1][w] = r; sm[2][w] = n; }
  __syncthreads();
  if (threadIdx.x == 0) {
    float tm = 0.f, tr = 0.f, tn = 0.f;
#pragma unroll
    for (int j = 0; j < kBlk / 64; ++j) { tm += sm[0][j]; tr += sm[1][j]; tn += sm[2][j]; }
    out[0] = tm + 5.0f * tr / fmaxf(tn, 1.0f);
  }
}

}  // namespace

extern "C" void kernel_launch(void* const* d_in, const int* in_sizes, int n_in,
                              void* d_out, int out_size, void* d_ws, size_t ws_size,
                              hipStream_t stream) {
  const float* outs     = (const float*)d_in[0];
  const float* gres     = (const float*)d_in[1];
  const float* grids    = (const float*)d_in[2];
  const int*   nums_pos = (const int*)d_in[3];
  float* partials = (float*)d_ws;  // kNT * 3 * 4 B = 24,576 B

  floss_fused<<<kNT, kBlk, 0, stream>>>(outs, gres, grids, nums_pos, partials);
  floss_final<<<1, kBlk, 0, stream>>>(partials, (float*)d_out);
}

// Round 7
// 64.386 us; speedup vs baseline: 1.2001x; 1.2001x over previous
//
#include <hip/hip_runtime.h>

namespace {

constexpr int   kC    = 80;
constexpr int   kD    = 8525;
constexpr int   kB    = 64;
constexpr float kEps  = 1e-6f;
constexpr int   kOC   = 85;                 // outs channels
constexpr int   kGC   = 88;                 // gres channels
constexpr int   kBlk  = 256;
constexpr int   kPB   = kD * kOC;           // floats of outs per batch item
constexpr int   kSpb  = 32;                 // slices (blocks) per batch item
constexpr int   kRPS  = (kD + kSpb - 1) / kSpb;  // 267 rows per slice
constexpr int   kNT   = kB * kSpb;          // 2048 blocks
constexpr int   kQCap = 96;                 // pos-row queue (mean ~27, +14 sigma)
constexpr int   kQW   = 9;                  // padded stride (bank-conflict-free)

constexpr float kLog2e = 1.44269504f;
constexpr float kLn2   = 0.69314718f;

__device__ __forceinline__ float wave_reduce(float v) {
#pragma unroll
  for (int o = 32; o > 0; o >>= 1) v += __shfl_down(v, o, 64);
  return v;
}

__device__ __forceinline__ float fast_rcp(float x) {
  return __builtin_amdgcn_rcpf(x);
}

// raw term: p^2 * log2(1-p+eps), p = sigmoid(x).  (caller applies ln2 & scale)
__device__ __forceinline__ float lneg2(float x) {
  const float t = __builtin_amdgcn_exp2f(x * -kLog2e);   // e^-x
  const float p = fast_rcp(1.0f + t);                    // sigmoid(x), <= 1
  return p * p * __builtin_amdgcn_logf(1.000001f - p);   // log2(1-p+eps)
}

__device__ __forceinline__ float lneg2_4(const float4 v) {
  return (lneg2(v.x) + lneg2(v.y)) + (lneg2(v.z) + lneg2(v.w));
}

__global__ __launch_bounds__(kBlk, 8) void floss_fused(
    const float* __restrict__ outs, const float* __restrict__ gres,
    const float* __restrict__ grids, const int* __restrict__ nums_pos,
    float* __restrict__ partials) {
  const int bid = blockIdx.x;          // 0..2047
  const int tid = threadIdx.x;
  const int b   = bid >> 5;
  const int sb  = bid & 31;
  const int r0  = sb * kRPS;
  const int r1  = (r0 + kRPS < kD) ? r0 + kRPS : kD;
  const int nrows = r1 - r0;
  const float scale = fast_rcp(64.0f * (float)nums_pos[b]);

  __shared__ float s_q[kQCap * kQW];
  __shared__ int   s_cnt;
  __shared__ float sm[3][kBlk / 64];
  if (tid == 0) s_cnt = 0;

  float accS = 0.f;   // stream: sum lneg2 over all 85 channels
  float accT = 0.f;   // tails:  sum lneg2 over channels 80..84 (to cancel)
  float pmO  = 0.f;   // conf + pos-correction terms (scaled as computed)
  float pr = 0.f, pn = 0.f;

  // ---------------- phase A: branchless lneg2 stream, 4-deep MLP ----------
  auto streamPhase = [&]() {
    const int gA = b * kPB + r0 * kOC;
    const int gB = b * kPB + r1 * kOC;
    const int gv = (gA + 3) & ~3;
    const int nvec = (gB - gv) >> 2;
    const int gvend = gv + (nvec << 2);
    float a0 = 0.f, a1 = 0.f, a2 = 0.f, a3 = 0.f;
    if (tid < gv - gA)    a0 += lneg2(outs[gA + tid]);
    if (tid < gB - gvend) a1 += lneg2(outs[gvend + tid]);
    const float4* pv = (const float4*)(outs + gv);
    int v = tid;
    for (; v + 3 * kBlk < nvec; v += 4 * kBlk) {
      const float4 xa = pv[v];
      const float4 xb = pv[v + kBlk];
      const float4 xc = pv[v + 2 * kBlk];
      const float4 xd = pv[v + 3 * kBlk];
      a0 += lneg2_4(xa);
      a1 += lneg2_4(xb);
      a2 += lneg2_4(xc);
      a3 += lneg2_4(xd);
    }
    for (; v < nvec; v += kBlk) a0 += lneg2_4(pv[v]);
    accS += (a0 + a1) + (a2 + a3);
  };

  // ---------------- phase B stage 1: one row per lane ---------------------
  auto rowStage1 = [&]() {
    for (int rl = tid; rl < nrows; rl += kBlk) {
      const int r   = r0 + rl;
      const int row = b * kD + r;
      const float4 xt  = *(const float4*)(outs + (size_t)row * kOC + 80);
      const float  x84 = outs[(size_t)row * kOC + 84];
      const float4 t1  = *(const float4*)(gres + (size_t)row * kGC + 84);
      accT += ((lneg2(xt.x) + lneg2(xt.y)) +
               (lneg2(xt.z) + lneg2(xt.w))) + lneg2(x84);
      if (t1.y == 1.0f) {  // mask_pp -> conf BCE on x80
        const float pc = fast_rcp(1.0f + __expf(-xt.x));
        pmO += -5.0f * __logf(pc + kEps) * scale;
      }
      if (t1.z == 1.0f) {  // mask_pos -> queue
        pn += 1.0f;
        const int slot = atomicAdd(&s_cnt, 1);
        if (slot < kQCap) {
          float* q = s_q + slot * kQW;
          const float2 gxy = *(const float2*)(grids + 2 * r);
          q[0] = __int_as_float(row);
          q[1] = xt.y; q[2] = xt.z; q[3] = xt.w; q[4] = x84;  // pred offsets
          q[5] = gxy.x; q[6] = gxy.y;
          q[7] = t1.x;                                        // g_ltrb bottom
        }
      }
    }
  };

  // ---------------- phase B stage 2: half-wave per queued pos row ---------
  auto rowStage2 = [&]() {
    const int nq = (s_cnt < kQCap) ? s_cnt : kQCap;
    const int hh = tid >> 5;
    const int h  = tid & 31;
    for (int e = hh; e < nq; e += 8) {
      const float* q = s_q + e * kQW;
      const int row = __float_as_int(q[0]);
      int cand = -1;
      float4 v = make_float4(0.f, 0.f, 0.f, 0.f);
      if (h < 20) {
        v = *(const float4*)(gres + (size_t)row * kGC + 4 * h);
        if (v.x == 1.0f) cand = 4 * h;
        if (v.y == 1.0f) cand = 4 * h + 1;
        if (v.z == 1.0f) cand = 4 * h + 2;
        if (v.w == 1.0f) cand = 4 * h + 3;
      } else if (h == 20) {
        v = *(const float4*)(gres + (size_t)row * kGC + 80);  // gcen,l,t,r
      }
#pragma unroll
      for (int m = 16; m > 0; m >>= 1) {
        const int o = __shfl_xor(cand, m, 32);
        cand = (o > cand) ? o : cand;
      }
      if (h == 20 && cand >= 0) {
        // correction at label channel: + l_pos - l_neg
        const float x  = outs[(size_t)row * kOC + cand];
        const float p  = fast_rcp(1.0f + __expf(-x));
        const float om = 1.0f - p;
        const float lp = -0.25f * om * om * __logf(p + kEps);
        const float ln = -0.75f * p * p * __logf(om + kEps);
        pmO += (lp - ln) * scale;
        // GIoU regression
        const float gx = q[5], gy = q[6];
        const float p0 = gx - q[1], p1 = gy - q[2];
        const float p2 = gx + q[3], p3 = gy + q[4];
        const float g0 = v.y, g1 = v.z, g2 = v.w, g3 = q[7];
        const float iw = fmaxf(fminf(p2, g2) - fmaxf(p0, g0), 0.f);
        const float ih = fmaxf(fminf(p3, g3) - fmaxf(p1, g1), 0.f);
        const float inter = iw * ih;
        const float ap = fmaxf(p2 - p0, 0.f) * fmaxf(p3 - p1, 0.f);
        const float ag = fmaxf(g2 - g0, 0.f) * fmaxf(g3 - g1, 0.f);
        const float un = ap + ag - inter;
        const float iou = inter * fast_rcp(un + kEps);
        const float ca = (fmaxf(p2, g2) - fminf(p0, g0)) *
                         (fmaxf(p3, g3) - fminf(p1, g1));
        const float giou = iou - (ca - un) * fast_rcp(ca + kEps);
        pr += (1.0f - giou) * v.x;
      }
    }
  };

  // ---------------- staggered phase order per block -----------------------
  if (((bid >> 8) ^ bid) & 1) {
    streamPhase();
    __syncthreads();        // s_cnt init visible
    rowStage1();
    __syncthreads();
    rowStage2();
  } else {
    __syncthreads();        // s_cnt init visible
    rowStage1();
    __syncthreads();
    rowStage2();
    streamPhase();
  }

  // pm: cancel tails before scaling; apply ln2 * 0.75 * scale once
  float pm = 0.75f * kLn2 * scale * (accT - accS) + pmO;

  // ---------------- block reduction + partial write -----------------------
  const float vm = wave_reduce(pm);
  const float vr = wave_reduce(pr);
  const float vn = wave_reduce(pn);
  const int lane = tid & 63;
  const int w    = tid >> 6;
  if (lane == 0) { sm[0][w] = vm; sm[1][w] = vr; sm[2][w] = vn; }
  __syncthreads();
  if (tid == 0) {
    float m = 0.f, r = 0.f, n = 0.f;
#pragma unroll
    for (int j = 0; j < kBlk / 64; ++j) { m += sm[0][j]; r += sm[1][j]; n += sm[2][j]; }
    partials[bid * 3 + 0] = m;
    partials[bid * 3 + 1] = r;
    partials[bid * 3 + 2] = n;
  }
}

__global__ __launch_bounds__(kBlk) void floss_final(
    const float* __restrict__ partials, float* __restrict__ out) {
  float m = 0.f, r = 0.f, n = 0.f;
  for (int i = threadIdx.x; i < kNT; i += kBlk) {
    m += partials[i * 3 + 0];
    r += partials[i * 3 + 1];
    n += partials[i * 3 + 2];
  }
  __shared__ float sm[3][kBlk / 64];
  m = wave_reduce(m); r = wave_reduce(r); n = wave_reduce(n);
  const int lane = threadIdx.x & 63;
  const int w    = threadIdx.x >> 6;
  if (lane == 0) { sm[0][w] = m; sm[1][w] = r; sm[2][w] = n; }
  __syncthreads();
  if (threadIdx.x == 0) {
    float tm = 0.f, tr = 0.f, tn = 0.f;
#pragma unroll
    for (int j = 0; j < kBlk / 64; ++j) { tm += sm[0][j]; tr += sm[1][j]; tn += sm[2][j]; }
    out[0] = tm + 5.0f * tr / fmaxf(tn, 1.0f);
  }
}

}  // namespace

extern "C" void kernel_launch(void* const* d_in, const int* in_sizes, int n_in,
                              void* d_out, int out_size, void* d_ws, size_t ws_size,
                              hipStream_t stream) {
  const float* outs     = (const float*)d_in[0];
  const float* gres     = (const float*)d_in[1];
  const float* grids    = (const float*)d_in[2];
  const int*   nums_pos = (const int*)d_in[3];
  float* partials = (float*)d_ws;  // kNT * 3 * 4 B = 24,576 B

  floss_fused<<<kNT, kBlk, 0, stream>>>(outs, gres, grids, nums_pos, partials);
  floss_final<<<1, kBlk, 0, stream>>>(partials, (float*)d_out);
}